// Round 2
// baseline (470.048 us; speedup 1.0000x reference)
//
#include <hip/hip_runtime.h>
#include <math.h>

// Problem constants (from reference setup_inputs)
#define BB    8
#define DIN   1024
#define TT    2048
#define DCB   64
#define VV    8192
#define NN    (BB * TT)      // 16384 rows
#define EPSN  1e-12f

#define NCHUNK 16
#define CPC    (VV / NCHUNK) // 512 codes per chunk

// ---------------------------------------------------------------------------
// Kernel 1: normalize codebook rows -> cn, and cn2 = sum(cn*cn) per row.
// One wave (64 lanes) per codebook row; lane k holds element k.
// ---------------------------------------------------------------------------
__global__ void __launch_bounds__(256) k_prep_cb(const float* __restrict__ cb,
                                                 float* __restrict__ cn,
                                                 float* __restrict__ cn2) {
    int v    = blockIdx.x * 4 + (threadIdx.x >> 6);
    int k    = threadIdx.x & 63;
    float x  = cb[v * DCB + k];
    float s  = x * x;
    #pragma unroll
    for (int off = 32; off; off >>= 1) s += __shfl_xor(s, off, 64);
    float nrm = sqrtf(s);
    float den = fmaxf(nrm, EPSN);
    float c   = x / den;
    cn[v * DCB + k] = c;
    float s2 = c * c;
    #pragma unroll
    for (int off = 32; off; off >>= 1) s2 += __shfl_xor(s2, off, 64);
    if (k == 0) cn2[v] = s2;
}

// ---------------------------------------------------------------------------
// Kernel 2: transpose W [DCB, DIN] -> wt [DIN, DCB]
// ---------------------------------------------------------------------------
__global__ void __launch_bounds__(256) k_prep_wt(const float* __restrict__ W,
                                                 float* __restrict__ wt) {
    int i = blockIdx.x * 256 + threadIdx.x;   // 0 .. DIN*DCB-1
    int d = i >> 10;                          // 0..63   (reads coalesced over c)
    int c = i & 1023;
    wt[c * DCB + d] = W[d * DIN + c];
}

// ---------------------------------------------------------------------------
// Kernel 3: z_e = W z + b, then L2-normalize each row; store en and en2.
// Thread <-> (row n, d-octet). 8 consecutive lanes share a row.
// ---------------------------------------------------------------------------
__global__ void __launch_bounds__(256) k_gemm_norm(const float* __restrict__ z,
                                                   const float* __restrict__ wt,
                                                   const float* __restrict__ bias,
                                                   float* __restrict__ en,
                                                   float* __restrict__ en2) {
    int gid  = blockIdx.x * 256 + threadIdx.x;  // 0 .. 131071
    int n    = gid >> 3;                        // row 0..16383
    int d0   = (gid & 7) * 8;                   // d offset 0,8,...,56
    int b    = n >> 11;                         // n / TT
    int t    = n & 2047;                        // n % TT

    const float* zp = z + (size_t)b * DIN * TT + t;

    float acc[8];
    #pragma unroll
    for (int j = 0; j < 8; ++j) acc[j] = 0.0f;

    #pragma unroll 4
    for (int c = 0; c < DIN; ++c) {
        float zv = zp[(size_t)c * TT];
        const float4* wp = (const float4*)(wt + c * DCB + d0);
        float4 w0 = wp[0];
        float4 w1 = wp[1];
        acc[0] = fmaf(zv, w0.x, acc[0]);
        acc[1] = fmaf(zv, w0.y, acc[1]);
        acc[2] = fmaf(zv, w0.z, acc[2]);
        acc[3] = fmaf(zv, w0.w, acc[3]);
        acc[4] = fmaf(zv, w1.x, acc[4]);
        acc[5] = fmaf(zv, w1.y, acc[5]);
        acc[6] = fmaf(zv, w1.z, acc[6]);
        acc[7] = fmaf(zv, w1.w, acc[7]);
    }

    // add bias
    float ze[8];
    #pragma unroll
    for (int j = 0; j < 8; ++j) ze[j] = acc[j] + bias[d0 + j];

    // row sum of squares across the 8 lanes sharing this row
    float ss = 0.0f;
    #pragma unroll
    for (int j = 0; j < 8; ++j) ss = fmaf(ze[j], ze[j], ss);
    ss += __shfl_xor(ss, 1, 64);
    ss += __shfl_xor(ss, 2, 64);
    ss += __shfl_xor(ss, 4, 64);

    float den = fmaxf(sqrtf(ss), EPSN);

    float e[8];
    #pragma unroll
    for (int j = 0; j < 8; ++j) e[j] = ze[j] / den;

    // en2 = sum(en*en) over the row (mirrors reference recompute)
    float s2 = 0.0f;
    #pragma unroll
    for (int j = 0; j < 8; ++j) s2 = fmaf(e[j], e[j], s2);
    s2 += __shfl_xor(s2, 1, 64);
    s2 += __shfl_xor(s2, 2, 64);
    s2 += __shfl_xor(s2, 4, 64);

    float4* ep = (float4*)(en + (size_t)n * DCB + d0);
    ep[0] = make_float4(e[0], e[1], e[2], e[3]);
    ep[1] = make_float4(e[4], e[5], e[6], e[7]);
    if ((gid & 7) == 0) en2[n] = s2;
}

// ---------------------------------------------------------------------------
// Kernel 4: distances + per-chunk argmax.
// Lane <-> row: each lane holds its whole en row (64 f32) in VGPRs.
// Codebook row cn[v][*] is wave-uniform -> scalar loads feeding v_fmac(s,v).
// ---------------------------------------------------------------------------
__global__ void __launch_bounds__(256) k_dist(const float* __restrict__ en,
                                              const float* __restrict__ en2g,
                                              const float* __restrict__ cn,
                                              const float* __restrict__ cn2,
                                              float* __restrict__ pscore,
                                              int* __restrict__ pidx) {
    int wave  = threadIdx.x >> 6;
    int lane  = threadIdx.x & 63;
    int n     = blockIdx.x * 256 + wave * 64 + lane;  // row
    int chunk = blockIdx.y;                           // 0..NCHUNK-1

    float e[64];
    const float4* ep = (const float4*)(en + (size_t)n * DCB);
    #pragma unroll
    for (int i = 0; i < 16; ++i) {
        float4 v4 = ep[i];
        e[4 * i + 0] = v4.x;
        e[4 * i + 1] = v4.y;
        e[4 * i + 2] = v4.z;
        e[4 * i + 3] = v4.w;
    }
    float den2 = en2g[n];

    float best = -INFINITY;
    int   bidx = 0;

    int v0 = chunk * CPC;
    for (int v = v0; v < v0 + CPC; ++v) {
        const float4* cp = (const float4*)(cn + v * DCB);  // uniform address
        float a0 = 0.0f, a1 = 0.0f, a2 = 0.0f, a3 = 0.0f;
        #pragma unroll
        for (int i = 0; i < 16; ++i) {
            float4 cv = cp[i];
            a0 = fmaf(e[4 * i + 0], cv.x, a0);
            a1 = fmaf(e[4 * i + 1], cv.y, a1);
            a2 = fmaf(e[4 * i + 2], cv.z, a2);
            a3 = fmaf(e[4 * i + 3], cv.w, a3);
        }
        float dot  = (a0 + a1) + (a2 + a3);
        // mirror reference: dist = (en2 - 2*dot) + cn2
        float dist = fmaf(-2.0f, dot, den2) + cn2[v];
        float nd   = -dist;
        if (nd > best) { best = nd; bidx = v; }
    }

    pscore[(size_t)chunk * NN + n] = best;
    pidx  [(size_t)chunk * NN + n] = bidx;
}

// ---------------------------------------------------------------------------
// Kernel 5: combine the NCHUNK per-chunk winners (ascending chunk order keeps
// first-index tie-break identical to jnp.argmax). Output dtype is int32.
// ---------------------------------------------------------------------------
__global__ void __launch_bounds__(256) k_reduce(const float* __restrict__ pscore,
                                                const int* __restrict__ pidx,
                                                int* __restrict__ out) {
    int n = blockIdx.x * 256 + threadIdx.x;  // 0..16383
    float best = -INFINITY;
    int   bi   = 0;
    #pragma unroll
    for (int c = 0; c < NCHUNK; ++c) {
        float s = pscore[(size_t)c * NN + n];
        int  id = pidx [(size_t)c * NN + n];
        if (s > best) { best = s; bi = id; }
    }
    out[n] = bi;   // int32 — harness reads d_out as int32 for integer outputs
}

// ---------------------------------------------------------------------------
extern "C" void kernel_launch(void* const* d_in, const int* in_sizes, int n_in,
                              void* d_out, int out_size, void* d_ws, size_t ws_size,
                              hipStream_t stream) {
    const float* z  = (const float*)d_in[0];  // [8,1024,2048]
    const float* W  = (const float*)d_in[1];  // [64,1024]
    const float* bi = (const float*)d_in[2];  // [64]
    const float* cb = (const float*)d_in[3];  // [8192,64]
    int* out = (int*)d_out;                   // [16384] indices, int32

    char* ws = (char*)d_ws;
    float* cn     = (float*)(ws);                                   // 2 MB
    float* cn2    = (float*)(ws + 2097152);                         // 32 KB
    float* wt     = (float*)(ws + 2097152 + 32768);                 // 256 KB
    float* en     = (float*)(ws + 2097152 + 32768 + 262144);        // 4 MB
    float* en2    = (float*)(ws + 2097152 + 32768 + 262144 + 4194304);        // 64 KB
    float* pscore = (float*)(ws + 2097152 + 32768 + 262144 + 4194304 + 65536);// 1 MB
    int*   pidx   = (int*)  (ws + 2097152 + 32768 + 262144 + 4194304 + 65536 + 1048576); // 1 MB

    hipLaunchKernelGGL(k_prep_cb,   dim3(VV / 4),      dim3(256), 0, stream, cb, cn, cn2);
    hipLaunchKernelGGL(k_prep_wt,   dim3(DIN * DCB / 256), dim3(256), 0, stream, W, wt);
    hipLaunchKernelGGL(k_gemm_norm, dim3(NN * 8 / 256), dim3(256), 0, stream, z, wt, bi, en, en2);
    hipLaunchKernelGGL(k_dist,      dim3(NN / 256, NCHUNK), dim3(256), 0, stream,
                       en, en2, cn, cn2, pscore, pidx);
    hipLaunchKernelGGL(k_reduce,    dim3(NN / 256),    dim3(256), 0, stream, pscore, pidx, out);
}

// Round 3
// 450.880 us; speedup vs baseline: 1.0425x; 1.0425x over previous
//
#include <hip/hip_runtime.h>
#include <math.h>

// Problem constants (from reference setup_inputs)
#define BB    8
#define DIN   1024
#define TT    2048
#define DCB   64
#define VV    8192
#define NN    (BB * TT)      // 16384 rows
#define EPSN  1e-12f

#define NCHUNK 16
#define CPC    (VV / NCHUNK) // 512 codes per chunk

// ---------------------------------------------------------------------------
// Kernel 1: normalize codebook rows -> cn, and cn2 = sum(cn*cn) per row.
// One wave (64 lanes) per codebook row; lane k holds element k.
// ---------------------------------------------------------------------------
__global__ void __launch_bounds__(256) k_prep_cb(const float* __restrict__ cb,
                                                 float* __restrict__ cn,
                                                 float* __restrict__ cn2) {
    int v    = blockIdx.x * 4 + (threadIdx.x >> 6);
    int k    = threadIdx.x & 63;
    float x  = cb[v * DCB + k];
    float s  = x * x;
    #pragma unroll
    for (int off = 32; off; off >>= 1) s += __shfl_xor(s, off, 64);
    float nrm = sqrtf(s);
    float den = fmaxf(nrm, EPSN);
    float c   = x / den;
    cn[v * DCB + k] = c;
    float s2 = c * c;
    #pragma unroll
    for (int off = 32; off; off >>= 1) s2 += __shfl_xor(s2, off, 64);
    if (k == 0) cn2[v] = s2;
}

// ---------------------------------------------------------------------------
// Kernel 2: transpose W [DCB, DIN] -> wt [DIN, DCB]
// ---------------------------------------------------------------------------
__global__ void __launch_bounds__(256) k_prep_wt(const float* __restrict__ W,
                                                 float* __restrict__ wt) {
    int i = blockIdx.x * 256 + threadIdx.x;   // 0 .. DIN*DCB-1
    int d = i >> 10;                          // 0..63
    int c = i & 1023;
    wt[c * DCB + d] = W[d * DIN + c];
}

// ---------------------------------------------------------------------------
// Kernel 3: z_e = W z + b, then L2-normalize each row; store en and en2.
// NEW MAPPING: row = lane (64 consecutive t per wave -> coalesced z reads),
// d-octet = wave index (W/bias loads wave-uniform -> scalar).
// Cross-wave row reduction via padded LDS.
// ---------------------------------------------------------------------------
__global__ void __launch_bounds__(512) k_gemm_norm(const float* __restrict__ z,
                                                   const float* __restrict__ wt,
                                                   const float* __restrict__ bias,
                                                   float* __restrict__ en,
                                                   float* __restrict__ en2) {
    __shared__ float red[64][9];   // [row][oct], padded to kill bank conflicts

    int r   = threadIdx.x & 63;    // row within block == lane
    int oct = threadIdx.x >> 6;    // 0..7 == wave index
    int n   = blockIdx.x * 64 + r; // global row
    int b   = n >> 11;             // n / TT
    int t   = n & 2047;            // n % TT
    int d0  = oct * 8;

    const float* zp = z + (size_t)b * (DIN * TT) + t;

    float acc[8];
    #pragma unroll
    for (int j = 0; j < 8; ++j) acc[j] = 0.0f;

    #pragma unroll 4
    for (int c = 0; c < DIN; ++c) {
        float zv = zp[(size_t)c * TT];                     // coalesced over lanes
        const float4* w4 = (const float4*)(wt + c * DCB + d0);  // wave-uniform
        float4 w0 = w4[0];
        float4 w1 = w4[1];
        acc[0] = fmaf(zv, w0.x, acc[0]);
        acc[1] = fmaf(zv, w0.y, acc[1]);
        acc[2] = fmaf(zv, w0.z, acc[2]);
        acc[3] = fmaf(zv, w0.w, acc[3]);
        acc[4] = fmaf(zv, w1.x, acc[4]);
        acc[5] = fmaf(zv, w1.y, acc[5]);
        acc[6] = fmaf(zv, w1.z, acc[6]);
        acc[7] = fmaf(zv, w1.w, acc[7]);
    }

    float ze[8];
    #pragma unroll
    for (int j = 0; j < 8; ++j) ze[j] = acc[j] + bias[d0 + j];

    // row sum of squares: partial per-thread, then across 8 octs via LDS
    float ss = 0.0f;
    #pragma unroll
    for (int j = 0; j < 8; ++j) ss = fmaf(ze[j], ze[j], ss);
    red[r][oct] = ss;
    __syncthreads();
    float tot = 0.0f;
    #pragma unroll
    for (int j = 0; j < 8; ++j) tot += red[r][j];
    float den = fmaxf(sqrtf(tot), EPSN);

    float e[8];
    #pragma unroll
    for (int j = 0; j < 8; ++j) e[j] = ze[j] / den;

    // en2 = sum(en*en) recomputed elementwise (mirrors reference)
    float s2 = 0.0f;
    #pragma unroll
    for (int j = 0; j < 8; ++j) s2 = fmaf(e[j], e[j], s2);
    __syncthreads();
    red[r][oct] = s2;
    __syncthreads();
    float tot2 = 0.0f;
    #pragma unroll
    for (int j = 0; j < 8; ++j) tot2 += red[r][j];

    float4* ep = (float4*)(en + (size_t)n * DCB + d0);
    ep[0] = make_float4(e[0], e[1], e[2], e[3]);
    ep[1] = make_float4(e[4], e[5], e[6], e[7]);
    if (oct == 0) en2[n] = tot2;
}

// ---------------------------------------------------------------------------
// Kernel 4: distances + per-chunk argmax.
// Lane <-> row. The en row lives in 16 NAMED float4s -> forced into VGPRs
// (the arrayed version was demoted to scratch: VGPR_Count was 40).
// Codebook row is wave-uniform -> scalar s_load feeding v_fmac(s,v).
// ---------------------------------------------------------------------------
__global__ void __launch_bounds__(256) k_dist(const float* __restrict__ en,
                                              const float* __restrict__ en2g,
                                              const float* __restrict__ cn,
                                              const float* __restrict__ cn2,
                                              float* __restrict__ pscore,
                                              int* __restrict__ pidx) {
    int n     = blockIdx.x * 256 + threadIdx.x;  // row
    int chunk = blockIdx.y;                      // 0..NCHUNK-1

    const float4* ep = (const float4*)(en + (size_t)n * DCB);
    float4 e0 = ep[0],  e1 = ep[1],  e2 = ep[2],  e3 = ep[3];
    float4 e4 = ep[4],  e5 = ep[5],  e6 = ep[6],  e7 = ep[7];
    float4 e8 = ep[8],  e9 = ep[9],  e10 = ep[10], e11 = ep[11];
    float4 e12 = ep[12], e13 = ep[13], e14 = ep[14], e15 = ep[15];
    float den2 = en2g[n];

    float best = -INFINITY;
    int   bidx = 0;

    int v0 = chunk * CPC;
    for (int v = v0; v < v0 + CPC; ++v) {
        const float4* cp = (const float4*)(cn + (size_t)v * DCB);  // uniform
        float a0 = 0.0f, a1 = 0.0f, a2 = 0.0f, a3 = 0.0f;
        #define VQ_STEP(E, i)                      \
            { float4 cv = cp[i];                   \
              a0 = fmaf(E.x, cv.x, a0);            \
              a1 = fmaf(E.y, cv.y, a1);            \
              a2 = fmaf(E.z, cv.z, a2);            \
              a3 = fmaf(E.w, cv.w, a3); }
        VQ_STEP(e0, 0)   VQ_STEP(e1, 1)   VQ_STEP(e2, 2)   VQ_STEP(e3, 3)
        VQ_STEP(e4, 4)   VQ_STEP(e5, 5)   VQ_STEP(e6, 6)   VQ_STEP(e7, 7)
        VQ_STEP(e8, 8)   VQ_STEP(e9, 9)   VQ_STEP(e10, 10) VQ_STEP(e11, 11)
        VQ_STEP(e12, 12) VQ_STEP(e13, 13) VQ_STEP(e14, 14) VQ_STEP(e15, 15)
        #undef VQ_STEP
        float dot  = (a0 + a1) + (a2 + a3);
        // mirror reference: dist = (en2 - 2*dot) + cn2
        float dist = fmaf(-2.0f, dot, den2) + cn2[v];
        float nd   = -dist;
        if (nd > best) { best = nd; bidx = v; }
    }

    pscore[(size_t)chunk * NN + n] = best;
    pidx  [(size_t)chunk * NN + n] = bidx;
}

// ---------------------------------------------------------------------------
// Kernel 5: combine per-chunk winners (ascending chunk order preserves
// first-index tie-break). Output dtype is int32.
// ---------------------------------------------------------------------------
__global__ void __launch_bounds__(256) k_reduce(const float* __restrict__ pscore,
                                                const int* __restrict__ pidx,
                                                int* __restrict__ out) {
    int n = blockIdx.x * 256 + threadIdx.x;  // 0..16383
    float best = -INFINITY;
    int   bi   = 0;
    #pragma unroll
    for (int c = 0; c < NCHUNK; ++c) {
        float s = pscore[(size_t)c * NN + n];
        int  id = pidx [(size_t)c * NN + n];
        if (s > best) { best = s; bi = id; }
    }
    out[n] = bi;
}

// ---------------------------------------------------------------------------
extern "C" void kernel_launch(void* const* d_in, const int* in_sizes, int n_in,
                              void* d_out, int out_size, void* d_ws, size_t ws_size,
                              hipStream_t stream) {
    const float* z  = (const float*)d_in[0];  // [8,1024,2048]
    const float* W  = (const float*)d_in[1];  // [64,1024]
    const float* bi = (const float*)d_in[2];  // [64]
    const float* cb = (const float*)d_in[3];  // [8192,64]
    int* out = (int*)d_out;                   // [16384] indices, int32

    char* ws = (char*)d_ws;
    float* cn     = (float*)(ws);                                   // 2 MB
    float* cn2    = (float*)(ws + 2097152);                         // 32 KB
    float* wt     = (float*)(ws + 2097152 + 32768);                 // 256 KB
    float* en     = (float*)(ws + 2097152 + 32768 + 262144);        // 4 MB
    float* en2    = (float*)(ws + 2097152 + 32768 + 262144 + 4194304);        // 64 KB
    float* pscore = (float*)(ws + 2097152 + 32768 + 262144 + 4194304 + 65536);// 1 MB
    int*   pidx   = (int*)  (ws + 2097152 + 32768 + 262144 + 4194304 + 65536 + 1048576); // 1 MB

    hipLaunchKernelGGL(k_prep_cb,   dim3(VV / 4),          dim3(256), 0, stream, cb, cn, cn2);
    hipLaunchKernelGGL(k_prep_wt,   dim3(DIN * DCB / 256), dim3(256), 0, stream, W, wt);
    hipLaunchKernelGGL(k_gemm_norm, dim3(NN / 64),         dim3(512), 0, stream, z, wt, bi, en, en2);
    hipLaunchKernelGGL(k_dist,      dim3(NN / 256, NCHUNK), dim3(256), 0, stream,
                       en, en2, cn, cn2, pscore, pidx);
    hipLaunchKernelGGL(k_reduce,    dim3(NN / 256),        dim3(256), 0, stream, pscore, pidx, out);
}